// Round 9
// baseline (431.814 us; speedup 1.0000x reference)
//
#include <hip/hip_runtime.h>
#include <math.h>

// Sizes: K=4, B=1024, C=128, T=64, D=64, H=4, HD=16, N=B*D=65536
#define EPSV 1e-5f

typedef __attribute__((ext_vector_type(8))) short short8;   // 8 x bf16 (4 VGPRs)
typedef __attribute__((ext_vector_type(4))) float float4v;  // MFMA 16x16 acc

__device__ __forceinline__ unsigned short f2bf(float f) {   // fp32 -> bf16 RNE
  unsigned int x = __float_as_uint(f);
  return (unsigned short)((x + 0x7fffu + ((x >> 16) & 1u)) >> 16);
}
__device__ __forceinline__ float bf2f(unsigned short u) {
  return __uint_as_float(((unsigned int)u) << 16);
}
__device__ __forceinline__ float wave_sum64(float v) {
  v += __shfl_xor(v, 1);
  v += __shfl_xor(v, 2);
  v += __shfl_xor(v, 4);
  v += __shfl_xor(v, 8);
  v += __shfl_xor(v, 16);
  v += __shfl_xor(v, 32);
  return v;
}
// sum over the 16-lane group (lanes sharing l>>4) — session-proven shfl form.
__device__ __forceinline__ float group16_sum(float v) {
  v += __shfl_xor(v, 1);
  v += __shfl_xor(v, 2);
  v += __shfl_xor(v, 4);
  v += __shfl_xor(v, 8);
  return v;
}
// Wave-level LDS fence: orders this wave's LDS writes before subsequent LDS
// reads (lanes are lockstep, so wave-private LDS needs no __syncthreads).
__device__ __forceinline__ void lds_fence() {
  asm volatile("s_waitcnt lgkmcnt(0)" ::: "memory");
}

// ---------------------------------------------------------------------------
// Kernel 0: one-time weight prep (proven round 2).
// ---------------------------------------------------------------------------
__global__ __launch_bounds__(256) void prep_kernel(
    const float* __restrict__ pw, const float* __restrict__ wq,
    const float* __restrict__ wk, const float* __restrict__ wv,
    const float* __restrict__ wo, unsigned short* __restrict__ wph,
    unsigned short* __restrict__ wpl, unsigned short* __restrict__ wb) {
  int idx = blockIdx.x * 256 + threadIdx.x;
  if (idx < 32768) {
    float f = pw[idx];
    unsigned short h = f2bf(f);
    wph[idx] = h;
    wpl[idx] = f2bf(f - bf2f(h));
  } else {
    int e = idx - 32768;
    int mat = e >> 14, i = (e >> 12) & 3, r = e & 4095;
    const float* src = (mat == 0) ? wq : (mat == 1) ? wk : (mat == 2) ? wv : wo;
    wb[((i * 4 + mat) << 12) + r] = f2bf(src[(i << 12) + r]);
  }
}

// ---------------------------------------------------------------------------
// Kernel 1: proj as split-bf16 MFMA, XOR-swizzled LDS (Cluster B item).
//   element (c,t) stored at  t*128 + ((c>>3)^(t&15))*8 + (c&7)
//   read fragment c=kc*32+lq*8+jj, t=nt*16+l15 -> same involution: value-
//   identical to the round-2 padded version, but balanced b128 banks and
//   dword-coalesced staging loads.
// ---------------------------------------------------------------------------
__global__ __launch_bounds__(256, 4) void proj_kernel(
    const float* __restrict__ feats, const unsigned short* __restrict__ wph,
    const unsigned short* __restrict__ wpl, const float* __restrict__ pb,
    unsigned short* __restrict__ ctxbf) {
  int kb = blockIdx.x;          // kb = k*1024 + b
  int k = kb >> 10;
  int b = kb & 1023;

  __shared__ __align__(16) unsigned short FH[64 * 128];   // swizzled [t][c] hi
  __shared__ __align__(16) unsigned short FL[64 * 128];   // swizzled [t][c] lo

  int tid = threadIdx.x;
  const float* fsrc = feats + (size_t)kb * 8192;
#pragma unroll
  for (int it = 0; it < 4; ++it) {
    int e = it * 256 + tid;     // 1024 units of 8 elements
    int t = e & 63;             // = lane (wave-uniform cg)
    int cg = e >> 6;            // c-block 0..15
    float fv[8];
#pragma unroll
    for (int q = 0; q < 8; ++q) fv[q] = fsrc[(cg * 8 + q) * 64 + t];  // coalesced
    short8 hv, lv;
#pragma unroll
    for (int q = 0; q < 8; ++q) {
      unsigned short h = f2bf(fv[q]);
      hv[q] = (short)h;
      lv[q] = (short)f2bf(fv[q] - bf2f(h));
    }
    int u = cg ^ (t & 15);
    *(short8*)&FH[t * 128 + u * 8] = hv;
    *(short8*)&FL[t * 128 + u * 8] = lv;
  }
  __syncthreads();

  int w = tid >> 6, l = tid & 63;
  int l15 = l & 15, lq = l >> 4;

  const float4v zf = {0.0f, 0.0f, 0.0f, 0.0f};
  float4v acc[4] = {zf, zf, zf, zf};                      // wave owns d-tile mt=w

  const unsigned short* whp = wph + k * 8192 + (w * 16 + l15) * 128 + lq * 8;
  const unsigned short* wlp = wpl + k * 8192 + (w * 16 + l15) * 128 + lq * 8;

  __builtin_amdgcn_s_setprio(1);
#pragma unroll
  for (int kc = 0; kc < 4; ++kc) {
    short8 ah = *(const short8*)&whp[kc * 32];
    short8 al = *(const short8*)&wlp[kc * 32];
#pragma unroll
    for (int nt = 0; nt < 4; ++nt) {
      int boff = (nt * 16 + l15) * 128 + (((kc * 4 + lq) ^ l15) * 8);
      short8 bh = *(const short8*)&FH[boff];
      short8 bl = *(const short8*)&FL[boff];
      acc[nt] = __builtin_amdgcn_mfma_f32_16x16x32_bf16(ah, bh, acc[nt], 0, 0, 0);
      acc[nt] = __builtin_amdgcn_mfma_f32_16x16x32_bf16(ah, bl, acc[nt], 0, 0, 0);
      acc[nt] = __builtin_amdgcn_mfma_f32_16x16x32_bf16(al, bh, acc[nt], 0, 0, 0);
    }
  }
  __builtin_amdgcn_s_setprio(0);

  float pbv[4];
#pragma unroll
  for (int r = 0; r < 4; ++r) pbv[r] = pb[k * 64 + w * 16 + lq * 4 + r];

  // d = w*16 + lq*4 + r, t = nt*16 + l15
  // ctx row n = b*64 + k*16 + w*4 + lq; col = r*64 + t
  size_t base = ((size_t)b * 64 + k * 16 + w * 4 + lq) * 256;
#pragma unroll
  for (int nt = 0; nt < 4; ++nt)
#pragma unroll
    for (int r = 0; r < 4; ++r)
      ctxbf[base + r * 64 + nt * 16 + l15] = f2bf(acc[nt][r] + pbv[r]);
}

// ---------------------------------------------------------------------------
// Kernel 2: MFMA attention — EXACT round-2 proven body (unroll-1 i-loop,
// per-module stores to out, separate final LN) + Cluster B:
// __launch_bounds__(256,3) and s_setprio around MFMA clusters.
// ---------------------------------------------------------------------------
__global__ __launch_bounds__(256, 3) void attn_fused(
    const unsigned short* __restrict__ ctxbf,
    const unsigned short* __restrict__ wb,
    const float* __restrict__ bq, const float* __restrict__ bk,
    const float* __restrict__ bv, const float* __restrict__ bo,
    const float* __restrict__ ng, const float* __restrict__ nb,
    const float* __restrict__ tfw, float* __restrict__ out) {
  __shared__ __align__(16) unsigned short CTP[64 * 264];   // ctx rows, pad 256->264
  __shared__ __align__(16) unsigned short OSP[4][16 * 72]; // per-wave o slab

  int tid = threadIdx.x;
  int w = tid >> 6, l = tid & 63;
  int l15 = l & 15, lq = l >> 4;

  // per-wave stage of this wave's 16 ctx rows
  {
    const unsigned short* csrc = ctxbf + ((size_t)blockIdx.x * 64 + w * 16) * 256;
#pragma unroll
    for (int u = 0; u < 8; ++u) {
      int e = u * 64 + l;
      int row = e >> 5, c8 = (e & 31) * 8;
      *(short8*)&CTP[(w * 16 + row) * 264 + c8] =
          *(const short8*)&csrc[row * 256 + c8];
    }
  }
  lds_fence();

  // softmax(tfw)
  float tf0 = tfw[0], tf1 = tfw[1], tf2 = tfw[2], tf3 = tfw[3];
  float tm = fmaxf(fmaxf(tf0, tf1), fmaxf(tf2, tf3));
  float te0 = __expf(tf0 - tm), te1 = __expf(tf1 - tm);
  float te2 = __expf(tf2 - tm), te3 = __expf(tf3 - tm);
  float tden = te0 + te1 + te2 + te3;

  const unsigned short* arow = &CTP[(w * 16 + l15) * 264];
  const float4v zf = {0.0f, 0.0f, 0.0f, 0.0f};

#pragma unroll 1
  for (int i = 0; i < 4; ++i) {
#define WFRAG(m, nt, s)                                                        \
  (*(const short8*)&wb[((i * 4 + (m)) << 12) + ((nt)*16 + l15) * 64 +          \
                       (s)*32 + lq * 8])

    float wi = ((i == 0) ? te0 : (i == 1) ? te1 : (i == 2) ? te2 : te3) / tden;

    float bqv[4], bkv[4], bvv[4];
#pragma unroll
    for (int nt = 0; nt < 4; ++nt) {
      int d = i * 64 + nt * 16 + l15;
      bqv[nt] = bq[d]; bkv[nt] = bk[d]; bvv[nt] = bv[d];
    }

    // ---- q = ctx[:,i] @ wq^T + bq ----
    float4v qacc[4] = {zf, zf, zf, zf};
    __builtin_amdgcn_s_setprio(1);
#pragma unroll
    for (int s = 0; s < 2; ++s) {
      short8 af = *(const short8*)&arow[i * 64 + s * 32 + lq * 8];
#pragma unroll
      for (int nt = 0; nt < 4; ++nt)
        qacc[nt] = __builtin_amdgcn_mfma_f32_16x16x32_bf16(af, WFRAG(0, nt, s),
                                                           qacc[nt], 0, 0, 0);
    }
    __builtin_amdgcn_s_setprio(0);
#pragma unroll
    for (int nt = 0; nt < 4; ++nt)
#pragma unroll
      for (int r = 0; r < 4; ++r) qacc[nt][r] += bqv[nt];

    // hoist K/V B-fragments into registers (round-2 proven form)
    short8 kf[2][4], vf[2][4];
#pragma unroll
    for (int s = 0; s < 2; ++s)
#pragma unroll
      for (int nt = 0; nt < 4; ++nt) {
        kf[s][nt] = WFRAG(1, nt, s);
        vf[s][nt] = WFRAG(2, nt, s);
      }

    // ---- per key j: k/v GEMMs, scores, un-normalized softmax-weighted V ----
    float4v oacc[4] = {zf, zf, zf, zf};
    float lsum[4][4] = {{0,0,0,0},{0,0,0,0},{0,0,0,0},{0,0,0,0}};

#pragma unroll 1
    for (int j = 0; j < 4; ++j) {
      float4v kacc[4] = {zf, zf, zf, zf};
      float4v vacc[4] = {zf, zf, zf, zf};
      __builtin_amdgcn_s_setprio(1);
#pragma unroll
      for (int s = 0; s < 2; ++s) {
        short8 af = *(const short8*)&arow[j * 64 + s * 32 + lq * 8];
#pragma unroll
        for (int nt = 0; nt < 4; ++nt) {
          kacc[nt] = __builtin_amdgcn_mfma_f32_16x16x32_bf16(af, kf[s][nt],
                                                             kacc[nt], 0, 0, 0);
          vacc[nt] = __builtin_amdgcn_mfma_f32_16x16x32_bf16(af, vf[s][nt],
                                                             vacc[nt], 0, 0, 0);
        }
      }
      __builtin_amdgcn_s_setprio(0);
#pragma unroll
      for (int nt = 0; nt < 4; ++nt)
#pragma unroll
        for (int r = 0; r < 4; ++r) {
          float p = qacc[nt][r] * (kacc[nt][r] + bkv[nt]);
          p = group16_sum(p) * 0.25f;          // 1/sqrt(HD); |p| small -> no max-sub
          float e = __expf(p);
          lsum[nt][r] += e;
          oacc[nt][r] += e * (vacc[nt][r] + bvv[nt]);
        }
    }

    // ---- o (C/D layout) -> plain [m][d] slab (wave-private, fence only) ----
    lds_fence();   // order vs previous iteration's OSP reads
#pragma unroll
    for (int nt = 0; nt < 4; ++nt)
#pragma unroll
      for (int r = 0; r < 4; ++r)
        OSP[w][(lq * 4 + r) * 72 + nt * 16 + l15] = f2bf(oacc[nt][r] / lsum[nt][r]);
    lds_fence();

    // ---- o2 = o @ wo^T ----
    float4v o2[4] = {zf, zf, zf, zf};
    __builtin_amdgcn_s_setprio(1);
#pragma unroll
    for (int s = 0; s < 2; ++s) {
      short8 af = *(const short8*)&OSP[w][l15 * 72 + s * 32 + lq * 8];
#pragma unroll
      for (int nt = 0; nt < 4; ++nt)
        o2[nt] = __builtin_amdgcn_mfma_f32_16x16x32_bf16(af, WFRAG(3, nt, s),
                                                         o2[nt], 0, 0, 0);
    }
    __builtin_amdgcn_s_setprio(0);

    float bov[4], ngv[4], nbv[4];
#pragma unroll
    for (int nt = 0; nt < 4; ++nt) {
      int d = i * 64 + nt * 16 + l15;
      bov[nt] = bo[d]; ngv[nt] = ng[d]; nbv[nt] = nb[d];
    }

    // ---- + bo + residual (plain CTP read) ----
    float rr[4][4];
#pragma unroll
    for (int nt = 0; nt < 4; ++nt)
#pragma unroll
      for (int r = 0; r < 4; ++r) {
        float qin = bf2f(CTP[(w * 16 + lq * 4 + r) * 264 + i * 64 + nt * 16 + l15]);
        rr[nt][r] = o2[nt][r] + bov[nt] + qin;
      }

    // ---- per-module LN over 64 dims of row m = lq*4+r; scale by wi; store ----
#pragma unroll
    for (int r = 0; r < 4; ++r) {
      float sm = group16_sum(rr[0][r] + rr[1][r] + rr[2][r] + rr[3][r]) * (1.0f / 64.0f);
      float vs = 0.0f;
#pragma unroll
      for (int nt = 0; nt < 4; ++nt) { float dx = rr[nt][r] - sm; vs += dx * dx; }
      vs = group16_sum(vs) * (1.0f / 64.0f);
      float inv = rsqrtf(vs + EPSV);
      size_t row = (size_t)blockIdx.x * 64 + w * 16 + lq * 4 + r;
#pragma unroll
      for (int nt = 0; nt < 4; ++nt) {
        float val = wi * ((rr[nt][r] - sm) * inv * ngv[nt] + nbv[nt]);
        out[row * 256 + i * 64 + nt * 16 + l15] = val;
      }
    }
#undef WFRAG
  }
}

// ---------------------------------------------------------------------------
// Kernel 3 (proven): final LN over K*D=256, in place.
// ---------------------------------------------------------------------------
__global__ __launch_bounds__(256, 4) void final_ln_kernel(
    float* __restrict__ out, const float* __restrict__ fg,
    const float* __restrict__ fb) {
  int lane = threadIdx.x & 63;
  int wave = threadIdx.x >> 6;
  size_t n = (size_t)blockIdx.x * 4 + wave;

  float4 v = *(const float4*)&out[n * 256 + lane * 4];
  float mean = wave_sum64(v.x + v.y + v.z + v.w) * (1.0f / 256.0f);
  float dx = v.x - mean, dy = v.y - mean, dz = v.z - mean, dw = v.w - mean;
  float var = wave_sum64(dx * dx + dy * dy + dz * dz + dw * dw) * (1.0f / 256.0f);
  float inv = rsqrtf(var + EPSV);

  float4 g = *(const float4*)&fg[lane * 4];
  float4 bb = *(const float4*)&fb[lane * 4];
  float4 o;
  o.x = dx * inv * g.x + bb.x;
  o.y = dy * inv * g.y + bb.y;
  o.z = dz * inv * g.z + bb.z;
  o.w = dw * inv * g.w + bb.w;
  *(float4*)&out[n * 256 + lane * 4] = o;
}

// ---------------------------------------------------------------------------
extern "C" void kernel_launch(void* const* d_in, const int* in_sizes, int n_in,
                              void* d_out, int out_size, void* d_ws, size_t ws_size,
                              hipStream_t stream) {
  const float* feats  = (const float*)d_in[0];
  const float* proj_w = (const float*)d_in[1];
  const float* proj_b = (const float*)d_in[2];
  const float* wq  = (const float*)d_in[3];
  const float* wk  = (const float*)d_in[4];
  const float* wv  = (const float*)d_in[5];
  const float* bq  = (const float*)d_in[6];
  const float* bk  = (const float*)d_in[7];
  const float* bv  = (const float*)d_in[8];
  const float* wo  = (const float*)d_in[9];
  const float* bo  = (const float*)d_in[10];
  const float* ng  = (const float*)d_in[11];
  const float* nb  = (const float*)d_in[12];
  const float* tfw = (const float*)d_in[13];
  const float* fg  = (const float*)d_in[14];
  const float* fb  = (const float*)d_in[15];
  float* out = (float*)d_out;

  // workspace: ctx_bf 32MB | wph 64KB | wpl 64KB | wb 128KB
  unsigned short* ctxbf = (unsigned short*)d_ws;
  unsigned short* wph = (unsigned short*)((char*)d_ws + ((size_t)32 << 20));
  unsigned short* wpl = wph + 32768;
  unsigned short* wb  = wpl + 32768;

  prep_kernel<<<384, 256, 0, stream>>>(proj_w, wq, wk, wv, wo, wph, wpl, wb);
  proj_kernel<<<4096, 256, 0, stream>>>(feats, wph, wpl, proj_b, ctxbf);
  attn_fused<<<1024, 256, 0, stream>>>(ctxbf, wb, bq, bk, bv, bo,
                                       ng, nb, tfw, out);
  final_ln_kernel<<<16384, 256, 0, stream>>>(out, fg, fb);
}

// Round 10
// 354.331 us; speedup vs baseline: 1.2187x; 1.2187x over previous
//
#include <hip/hip_runtime.h>
#include <math.h>

// Sizes: K=4, B=1024, C=128, T=64, D=64, H=4, HD=16, N=B*D=65536
#define EPSV 1e-5f

typedef __attribute__((ext_vector_type(8))) short short8;   // 8 x bf16 (4 VGPRs)
typedef __attribute__((ext_vector_type(4))) float float4v;  // MFMA 16x16 acc
typedef __attribute__((ext_vector_type(4))) unsigned short ushort4v;

__device__ __forceinline__ unsigned short f2bf(float f) {   // fp32 -> bf16 RNE
  unsigned int x = __float_as_uint(f);
  return (unsigned short)((x + 0x7fffu + ((x >> 16) & 1u)) >> 16);
}
__device__ __forceinline__ float bf2f(unsigned short u) {
  return __uint_as_float(((unsigned int)u) << 16);
}
__device__ __forceinline__ float wave_sum64(float v) {
  v += __shfl_xor(v, 1);
  v += __shfl_xor(v, 2);
  v += __shfl_xor(v, 4);
  v += __shfl_xor(v, 8);
  v += __shfl_xor(v, 16);
  v += __shfl_xor(v, 32);
  return v;
}
// sum over the 16-lane group (lanes sharing l>>4) — session-proven shfl form.
__device__ __forceinline__ float group16_sum(float v) {
  v += __shfl_xor(v, 1);
  v += __shfl_xor(v, 2);
  v += __shfl_xor(v, 4);
  v += __shfl_xor(v, 8);
  return v;
}
// Wave-level LDS fence: orders this wave's LDS writes before subsequent LDS
// reads (lanes are lockstep, so wave-private LDS needs no __syncthreads).
__device__ __forceinline__ void lds_fence() {
  asm volatile("s_waitcnt lgkmcnt(0)" ::: "memory");
}

// ---------------------------------------------------------------------------
// Kernel 0: one-time weight prep (proven).
// ---------------------------------------------------------------------------
__global__ __launch_bounds__(256) void prep_kernel(
    const float* __restrict__ pw, const float* __restrict__ wq,
    const float* __restrict__ wk, const float* __restrict__ wv,
    const float* __restrict__ wo, unsigned short* __restrict__ wph,
    unsigned short* __restrict__ wpl, unsigned short* __restrict__ wb) {
  int idx = blockIdx.x * 256 + threadIdx.x;
  if (idx < 32768) {
    float f = pw[idx];
    unsigned short h = f2bf(f);
    wph[idx] = h;
    wpl[idx] = f2bf(f - bf2f(h));
  } else {
    int e = idx - 32768;
    int mat = e >> 14, i = (e >> 12) & 3, r = e & 4095;
    const float* src = (mat == 0) ? wq : (mat == 1) ? wk : (mat == 2) ? wv : wo;
    wb[((i * 4 + mat) << 12) + r] = f2bf(src[(i << 12) + r]);
  }
}

// ---------------------------------------------------------------------------
// Kernel 1: proj as split-bf16 MFMA, XOR-swizzled LDS (R9-proven correct,
// perf-neutral vs padded). Same involution write/read (rule #21).
// ---------------------------------------------------------------------------
__global__ __launch_bounds__(256, 4) void proj_kernel(
    const float* __restrict__ feats, const unsigned short* __restrict__ wph,
    const unsigned short* __restrict__ wpl, const float* __restrict__ pb,
    unsigned short* __restrict__ ctxbf) {
  int kb = blockIdx.x;          // kb = k*1024 + b
  int k = kb >> 10;
  int b = kb & 1023;

  __shared__ __align__(16) unsigned short FH[64 * 128];   // swizzled [t][c] hi
  __shared__ __align__(16) unsigned short FL[64 * 128];   // swizzled [t][c] lo

  int tid = threadIdx.x;
  const float* fsrc = feats + (size_t)kb * 8192;
#pragma unroll
  for (int it = 0; it < 4; ++it) {
    int e = it * 256 + tid;     // 1024 units of 8 elements
    int t = e & 63;             // = lane (wave-uniform cg)
    int cg = e >> 6;            // c-block 0..15
    float fv[8];
#pragma unroll
    for (int q = 0; q < 8; ++q) fv[q] = fsrc[(cg * 8 + q) * 64 + t];  // coalesced
    short8 hv, lv;
#pragma unroll
    for (int q = 0; q < 8; ++q) {
      unsigned short h = f2bf(fv[q]);
      hv[q] = (short)h;
      lv[q] = (short)f2bf(fv[q] - bf2f(h));
    }
    int u = cg ^ (t & 15);
    *(short8*)&FH[t * 128 + u * 8] = hv;
    *(short8*)&FL[t * 128 + u * 8] = lv;
  }
  __syncthreads();

  int w = tid >> 6, l = tid & 63;
  int l15 = l & 15, lq = l >> 4;

  const float4v zf = {0.0f, 0.0f, 0.0f, 0.0f};
  float4v acc[4] = {zf, zf, zf, zf};                      // wave owns d-tile mt=w

  const unsigned short* whp = wph + k * 8192 + (w * 16 + l15) * 128 + lq * 8;
  const unsigned short* wlp = wpl + k * 8192 + (w * 16 + l15) * 128 + lq * 8;

  __builtin_amdgcn_s_setprio(1);
#pragma unroll
  for (int kc = 0; kc < 4; ++kc) {
    short8 ah = *(const short8*)&whp[kc * 32];
    short8 al = *(const short8*)&wlp[kc * 32];
#pragma unroll
    for (int nt = 0; nt < 4; ++nt) {
      int boff = (nt * 16 + l15) * 128 + (((kc * 4 + lq) ^ l15) * 8);
      short8 bh = *(const short8*)&FH[boff];
      short8 bl = *(const short8*)&FL[boff];
      acc[nt] = __builtin_amdgcn_mfma_f32_16x16x32_bf16(ah, bh, acc[nt], 0, 0, 0);
      acc[nt] = __builtin_amdgcn_mfma_f32_16x16x32_bf16(ah, bl, acc[nt], 0, 0, 0);
      acc[nt] = __builtin_amdgcn_mfma_f32_16x16x32_bf16(al, bh, acc[nt], 0, 0, 0);
    }
  }
  __builtin_amdgcn_s_setprio(0);

  float pbv[4];
#pragma unroll
  for (int r = 0; r < 4; ++r) pbv[r] = pb[k * 64 + w * 16 + lq * 4 + r];

  // d = w*16 + lq*4 + r, t = nt*16 + l15
  // ctx row n = b*64 + k*16 + w*4 + lq; col = r*64 + t
  size_t base = ((size_t)b * 64 + k * 16 + w * 4 + lq) * 256;
#pragma unroll
  for (int nt = 0; nt < 4; ++nt)
#pragma unroll
    for (int r = 0; r < 4; ++r)
      ctxbf[base + r * 64 + nt * 16 + l15] = f2bf(acc[nt][r] + pbv[r]);
}

// ---------------------------------------------------------------------------
// Kernel 2: MFMA attention — proven R2 body at __launch_bounds__(256,2)
// (NO forced-occupancy spill), unroll-1 i-loop, + LDS-comb fused final LN:
// per-module LN results go to CMB (same indices as the proven out-write,
// bf16), then each wave runs the proven final_ln reduction on its 16 rows.
// ---------------------------------------------------------------------------
__global__ __launch_bounds__(256, 2) void attn_fused(
    const unsigned short* __restrict__ ctxbf,
    const unsigned short* __restrict__ wb,
    const float* __restrict__ bq, const float* __restrict__ bk,
    const float* __restrict__ bv, const float* __restrict__ bo,
    const float* __restrict__ ng, const float* __restrict__ nb,
    const float* __restrict__ tfw, const float* __restrict__ fg,
    const float* __restrict__ fb, float* __restrict__ out) {
  __shared__ __align__(16) unsigned short CTP[64 * 264];   // 33792 B
  __shared__ __align__(16) unsigned short OSP[4][16 * 72]; // 9216 B
  __shared__ __align__(16) unsigned short CMB[64 * 256];   // 32768 B comb (bf16)

  int tid = threadIdx.x;
  int w = tid >> 6, l = tid & 63;
  int l15 = l & 15, lq = l >> 4;

  // per-wave stage of this wave's 16 ctx rows
  {
    const unsigned short* csrc = ctxbf + ((size_t)blockIdx.x * 64 + w * 16) * 256;
#pragma unroll
    for (int u = 0; u < 8; ++u) {
      int e = u * 64 + l;
      int row = e >> 5, c8 = (e & 31) * 8;
      *(short8*)&CTP[(w * 16 + row) * 264 + c8] =
          *(const short8*)&csrc[row * 256 + c8];
    }
  }
  lds_fence();

  // softmax(tfw)
  float tf0 = tfw[0], tf1 = tfw[1], tf2 = tfw[2], tf3 = tfw[3];
  float tm = fmaxf(fmaxf(tf0, tf1), fmaxf(tf2, tf3));
  float te0 = __expf(tf0 - tm), te1 = __expf(tf1 - tm);
  float te2 = __expf(tf2 - tm), te3 = __expf(tf3 - tm);
  float tden = te0 + te1 + te2 + te3;

  const unsigned short* arow = &CTP[(w * 16 + l15) * 264];
  const float4v zf = {0.0f, 0.0f, 0.0f, 0.0f};

#pragma unroll 1
  for (int i = 0; i < 4; ++i) {
#define WFRAG(m, nt, s)                                                        \
  (*(const short8*)&wb[((i * 4 + (m)) << 12) + ((nt)*16 + l15) * 64 +          \
                       (s)*32 + lq * 8])

    float wi = ((i == 0) ? te0 : (i == 1) ? te1 : (i == 2) ? te2 : te3) / tden;

    float bqv[4], bkv[4], bvv[4];
#pragma unroll
    for (int nt = 0; nt < 4; ++nt) {
      int d = i * 64 + nt * 16 + l15;
      bqv[nt] = bq[d]; bkv[nt] = bk[d]; bvv[nt] = bv[d];
    }

    // ---- q = ctx[:,i] @ wq^T + bq ----
    float4v qacc[4] = {zf, zf, zf, zf};
    __builtin_amdgcn_s_setprio(1);
#pragma unroll
    for (int s = 0; s < 2; ++s) {
      short8 af = *(const short8*)&arow[i * 64 + s * 32 + lq * 8];
#pragma unroll
      for (int nt = 0; nt < 4; ++nt)
        qacc[nt] = __builtin_amdgcn_mfma_f32_16x16x32_bf16(af, WFRAG(0, nt, s),
                                                           qacc[nt], 0, 0, 0);
    }
    __builtin_amdgcn_s_setprio(0);
#pragma unroll
    for (int nt = 0; nt < 4; ++nt)
#pragma unroll
      for (int r = 0; r < 4; ++r) qacc[nt][r] += bqv[nt];

    // hoist K/V B-fragments into registers (round-2 proven form)
    short8 kf[2][4], vf[2][4];
#pragma unroll
    for (int s = 0; s < 2; ++s)
#pragma unroll
      for (int nt = 0; nt < 4; ++nt) {
        kf[s][nt] = WFRAG(1, nt, s);
        vf[s][nt] = WFRAG(2, nt, s);
      }

    // ---- per key j: k/v GEMMs, scores, un-normalized softmax-weighted V ----
    float4v oacc[4] = {zf, zf, zf, zf};
    float lsum[4][4] = {{0,0,0,0},{0,0,0,0},{0,0,0,0},{0,0,0,0}};

#pragma unroll 1
    for (int j = 0; j < 4; ++j) {
      float4v kacc[4] = {zf, zf, zf, zf};
      float4v vacc[4] = {zf, zf, zf, zf};
      __builtin_amdgcn_s_setprio(1);
#pragma unroll
      for (int s = 0; s < 2; ++s) {
        short8 af = *(const short8*)&arow[j * 64 + s * 32 + lq * 8];
#pragma unroll
        for (int nt = 0; nt < 4; ++nt) {
          kacc[nt] = __builtin_amdgcn_mfma_f32_16x16x32_bf16(af, kf[s][nt],
                                                             kacc[nt], 0, 0, 0);
          vacc[nt] = __builtin_amdgcn_mfma_f32_16x16x32_bf16(af, vf[s][nt],
                                                             vacc[nt], 0, 0, 0);
        }
      }
      __builtin_amdgcn_s_setprio(0);
#pragma unroll
      for (int nt = 0; nt < 4; ++nt)
#pragma unroll
        for (int r = 0; r < 4; ++r) {
          float p = qacc[nt][r] * (kacc[nt][r] + bkv[nt]);
          p = group16_sum(p) * 0.25f;          // 1/sqrt(HD); |p| small -> no max-sub
          float e = __expf(p);
          lsum[nt][r] += e;
          oacc[nt][r] += e * (vacc[nt][r] + bvv[nt]);
        }
    }

    // ---- o (C/D layout) -> plain [m][d] slab (wave-private, fence only) ----
    lds_fence();   // order vs previous iteration's OSP reads
#pragma unroll
    for (int nt = 0; nt < 4; ++nt)
#pragma unroll
      for (int r = 0; r < 4; ++r)
        OSP[w][(lq * 4 + r) * 72 + nt * 16 + l15] = f2bf(oacc[nt][r] / lsum[nt][r]);
    lds_fence();

    // ---- o2 = o @ wo^T ----
    float4v o2[4] = {zf, zf, zf, zf};
    __builtin_amdgcn_s_setprio(1);
#pragma unroll
    for (int s = 0; s < 2; ++s) {
      short8 af = *(const short8*)&OSP[w][l15 * 72 + s * 32 + lq * 8];
#pragma unroll
      for (int nt = 0; nt < 4; ++nt)
        o2[nt] = __builtin_amdgcn_mfma_f32_16x16x32_bf16(af, WFRAG(3, nt, s),
                                                         o2[nt], 0, 0, 0);
    }
    __builtin_amdgcn_s_setprio(0);

    float bov[4], ngv[4], nbv[4];
#pragma unroll
    for (int nt = 0; nt < 4; ++nt) {
      int d = i * 64 + nt * 16 + l15;
      bov[nt] = bo[d]; ngv[nt] = ng[d]; nbv[nt] = nb[d];
    }

    // ---- + bo + residual (plain CTP read) ----
    float rr[4][4];
#pragma unroll
    for (int nt = 0; nt < 4; ++nt)
#pragma unroll
      for (int r = 0; r < 4; ++r) {
        float qin = bf2f(CTP[(w * 16 + lq * 4 + r) * 264 + i * 64 + nt * 16 + l15]);
        rr[nt][r] = o2[nt][r] + bov[nt] + qin;
      }

    // ---- per-module LN; scale by wi; store to CMB (same indices as the
    //      proven out-write, bf16 in LDS instead of fp32 in global) ----
#pragma unroll
    for (int r = 0; r < 4; ++r) {
      float sm = group16_sum(rr[0][r] + rr[1][r] + rr[2][r] + rr[3][r]) * (1.0f / 64.0f);
      float vs = 0.0f;
#pragma unroll
      for (int nt = 0; nt < 4; ++nt) { float dx = rr[nt][r] - sm; vs += dx * dx; }
      vs = group16_sum(vs) * (1.0f / 64.0f);
      float inv = rsqrtf(vs + EPSV);
      int rowl = w * 16 + lq * 4 + r;
#pragma unroll
      for (int nt = 0; nt < 4; ++nt) {
        float val = wi * ((rr[nt][r] - sm) * inv * ngv[nt] + nbv[nt]);
        CMB[rowl * 256 + i * 64 + nt * 16 + l15] = f2bf(val);
      }
    }
#undef WFRAG
  }

  // ---- fused final LN over K*D=256: proven final_ln reduction per row,
  //      reading this wave's 16 CMB rows (wave-private -> fence only) ----
  lds_fence();
  float4 g = *(const float4*)&fg[l * 4];
  float4 bb = *(const float4*)&fb[l * 4];
#pragma unroll 1
  for (int rr = 0; rr < 16; ++rr) {
    int rowl = w * 16 + rr;
    ushort4v pk = *(const ushort4v*)&CMB[rowl * 256 + l * 4];
    float vx = bf2f(pk.x), vy = bf2f(pk.y), vz = bf2f(pk.z), vw = bf2f(pk.w);
    float mean = wave_sum64(vx + vy + vz + vw) * (1.0f / 256.0f);
    float dx = vx - mean, dy = vy - mean, dz = vz - mean, dw = vw - mean;
    float var = wave_sum64(dx * dx + dy * dy + dz * dz + dw * dw) * (1.0f / 256.0f);
    float inv = rsqrtf(var + EPSV);
    float4 o;
    o.x = dx * inv * g.x + bb.x;
    o.y = dy * inv * g.y + bb.y;
    o.z = dz * inv * g.z + bb.z;
    o.w = dw * inv * g.w + bb.w;
    *(float4*)&out[((size_t)blockIdx.x * 64 + rowl) * 256 + l * 4] = o;
  }
}

// ---------------------------------------------------------------------------
extern "C" void kernel_launch(void* const* d_in, const int* in_sizes, int n_in,
                              void* d_out, int out_size, void* d_ws, size_t ws_size,
                              hipStream_t stream) {
  const float* feats  = (const float*)d_in[0];
  const float* proj_w = (const float*)d_in[1];
  const float* proj_b = (const float*)d_in[2];
  const float* wq  = (const float*)d_in[3];
  const float* wk  = (const float*)d_in[4];
  const float* wv  = (const float*)d_in[5];
  const float* bq  = (const float*)d_in[6];
  const float* bk  = (const float*)d_in[7];
  const float* bv  = (const float*)d_in[8];
  const float* wo  = (const float*)d_in[9];
  const float* bo  = (const float*)d_in[10];
  const float* ng  = (const float*)d_in[11];
  const float* nb  = (const float*)d_in[12];
  const float* tfw = (const float*)d_in[13];
  const float* fg  = (const float*)d_in[14];
  const float* fb  = (const float*)d_in[15];
  float* out = (float*)d_out;

  // workspace: ctx_bf 32MB | wph 64KB | wpl 64KB | wb 128KB
  unsigned short* ctxbf = (unsigned short*)d_ws;
  unsigned short* wph = (unsigned short*)((char*)d_ws + ((size_t)32 << 20));
  unsigned short* wpl = wph + 32768;
  unsigned short* wb  = wpl + 32768;

  prep_kernel<<<384, 256, 0, stream>>>(proj_w, wq, wk, wv, wo, wph, wpl, wb);
  proj_kernel<<<4096, 256, 0, stream>>>(feats, wph, wpl, proj_b, ctxbf);
  attn_fused<<<1024, 256, 0, stream>>>(ctxbf, wb, bq, bk, bv, bo,
                                       ng, nb, tfw, fg, fb, out);
}

// Round 11
// 343.530 us; speedup vs baseline: 1.2570x; 1.0314x over previous
//
#include <hip/hip_runtime.h>
#include <math.h>

// Sizes: K=4, B=1024, C=128, T=64, D=64, H=4, HD=16, N=B*D=65536
#define EPSV 1e-5f

typedef __attribute__((ext_vector_type(8))) short short8;   // 8 x bf16 (4 VGPRs)
typedef __attribute__((ext_vector_type(4))) float float4v;  // MFMA 16x16 acc
typedef __attribute__((ext_vector_type(4))) unsigned short ushort4v;

__device__ __forceinline__ unsigned short f2bf(float f) {   // fp32 -> bf16 RNE
  unsigned int x = __float_as_uint(f);
  return (unsigned short)((x + 0x7fffu + ((x >> 16) & 1u)) >> 16);
}
__device__ __forceinline__ float bf2f(unsigned short u) {
  return __uint_as_float(((unsigned int)u) << 16);
}
__device__ __forceinline__ float wave_sum64(float v) {
  v += __shfl_xor(v, 1);
  v += __shfl_xor(v, 2);
  v += __shfl_xor(v, 4);
  v += __shfl_xor(v, 8);
  v += __shfl_xor(v, 16);
  v += __shfl_xor(v, 32);
  return v;
}
// sum over the 16-lane group (lanes sharing l>>4) — session-proven shfl form.
__device__ __forceinline__ float group16_sum(float v) {
  v += __shfl_xor(v, 1);
  v += __shfl_xor(v, 2);
  v += __shfl_xor(v, 4);
  v += __shfl_xor(v, 8);
  return v;
}
// Wave-level LDS fence: orders this wave's LDS writes before subsequent LDS
// reads (lanes are lockstep, so wave-private LDS needs no __syncthreads).
__device__ __forceinline__ void lds_fence() {
  asm volatile("s_waitcnt lgkmcnt(0)" ::: "memory");
}

// ---------------------------------------------------------------------------
// Kernel 0: one-time weight prep (proven).
// ---------------------------------------------------------------------------
__global__ __launch_bounds__(256) void prep_kernel(
    const float* __restrict__ pw, const float* __restrict__ wq,
    const float* __restrict__ wk, const float* __restrict__ wv,
    const float* __restrict__ wo, unsigned short* __restrict__ wph,
    unsigned short* __restrict__ wpl, unsigned short* __restrict__ wb) {
  int idx = blockIdx.x * 256 + threadIdx.x;
  if (idx < 32768) {
    float f = pw[idx];
    unsigned short h = f2bf(f);
    wph[idx] = h;
    wpl[idx] = f2bf(f - bf2f(h));
  } else {
    int e = idx - 32768;
    int mat = e >> 14, i = (e >> 12) & 3, r = e & 4095;
    const float* src = (mat == 0) ? wq : (mat == 1) ? wk : (mat == 2) ? wv : wo;
    wb[((i * 4 + mat) << 12) + r] = f2bf(src[(i << 12) + r]);
  }
}

// ---------------------------------------------------------------------------
// Kernel 1: FUSED proj + attention + final LayerNorm.
// Block b: proj phase computes the 4 module tiles (proven R2 split-bf16 MFMA)
// writing bf16 directly into CTP (bit-identical to old ctx path); then the
// proven R10 attn phase (barrier-free, wave-private) + LDS-comb fused LN.
// FH/FL (proj staging, 34816 B) alias CMB (attn comb, 32768 B) -> POOL.
// LDS total: 34816 + 33792 + 9216 = 77824 B -> 2 blocks/CU.
// ---------------------------------------------------------------------------
__global__ __launch_bounds__(256, 2) void fused_kernel(
    const float* __restrict__ feats, const unsigned short* __restrict__ wph,
    const unsigned short* __restrict__ wpl, const float* __restrict__ pb,
    const unsigned short* __restrict__ wb,
    const float* __restrict__ bq, const float* __restrict__ bk,
    const float* __restrict__ bv, const float* __restrict__ bo,
    const float* __restrict__ ng, const float* __restrict__ nb,
    const float* __restrict__ tfw, const float* __restrict__ fg,
    const float* __restrict__ fb, float* __restrict__ out) {
  __shared__ __align__(16) unsigned short POOL[2 * 64 * 136]; // FH|FL / CMB
  __shared__ __align__(16) unsigned short CTP[64 * 264];      // ctx rows (bf16)
  __shared__ __align__(16) unsigned short OSP[4][16 * 72];    // per-wave o slab

  unsigned short* const FH = POOL;                 // [t][c] hi, pad 136
  unsigned short* const FL = POOL + 64 * 136;      // [t][c] lo
  unsigned short* const CMB = POOL;                // comb rows (attn phase only)

  int tid = threadIdx.x;
  int w = tid >> 6, l = tid & 63;
  int l15 = l & 15, lq = l >> 4;
  const float4v zf = {0.0f, 0.0f, 0.0f, 0.0f};

  // ======================= proj phase (4 modules) ==========================
#pragma unroll 1
  for (int k = 0; k < 4; ++k) {
    __syncthreads();   // FH/FL free (prev k's readers done; CMB not yet live)
    const float* fsrc = feats + ((size_t)k * 1024 + blockIdx.x) * 8192;
#pragma unroll
    for (int it = 0; it < 4; ++it) {
      int e = it * 256 + tid;     // 1024 units of 8 elements
      int t = e & 63;             // = lane within wave (coalesced loads)
      int cg = e >> 6;            // c-block 0..15
      float fv[8];
#pragma unroll
      for (int q = 0; q < 8; ++q) fv[q] = fsrc[(cg * 8 + q) * 64 + t];
      short8 hv, lv;
#pragma unroll
      for (int q = 0; q < 8; ++q) {
        unsigned short h = f2bf(fv[q]);
        hv[q] = (short)h;
        lv[q] = (short)f2bf(fv[q] - bf2f(h));
      }
      *(short8*)&FH[t * 136 + cg * 8] = hv;   // b128, conflict-benign
      *(short8*)&FL[t * 136 + cg * 8] = lv;
    }
    __syncthreads();

    float4v acc[4] = {zf, zf, zf, zf};        // wave owns d-tile mt=w
    const unsigned short* whp = wph + k * 8192 + (w * 16 + l15) * 128 + lq * 8;
    const unsigned short* wlp = wpl + k * 8192 + (w * 16 + l15) * 128 + lq * 8;

    __builtin_amdgcn_s_setprio(1);
#pragma unroll
    for (int kc = 0; kc < 4; ++kc) {
      short8 ah = *(const short8*)&whp[kc * 32];
      short8 al = *(const short8*)&wlp[kc * 32];
#pragma unroll
      for (int nt = 0; nt < 4; ++nt) {
        short8 bh = *(const short8*)&FH[(nt * 16 + l15) * 136 + kc * 32 + lq * 8];
        short8 bl = *(const short8*)&FL[(nt * 16 + l15) * 136 + kc * 32 + lq * 8];
        acc[nt] = __builtin_amdgcn_mfma_f32_16x16x32_bf16(ah, bh, acc[nt], 0, 0, 0);
        acc[nt] = __builtin_amdgcn_mfma_f32_16x16x32_bf16(ah, bl, acc[nt], 0, 0, 0);
        acc[nt] = __builtin_amdgcn_mfma_f32_16x16x32_bf16(al, bh, acc[nt], 0, 0, 0);
      }
    }
    __builtin_amdgcn_s_setprio(0);

    float pbv[4];
#pragma unroll
    for (int r = 0; r < 4; ++r) pbv[r] = pb[k * 64 + w * 16 + lq * 4 + r];

    // d = w*16+lq*4+r, t = nt*16+l15 -> CTP local row k*16+w*4+lq, col r*64+t
    // (bit-identical bf16 values to the old ctxbf->CTP path)
#pragma unroll
    for (int nt = 0; nt < 4; ++nt)
#pragma unroll
      for (int r = 0; r < 4; ++r)
        CTP[(k * 16 + w * 4 + lq) * 264 + r * 64 + nt * 16 + l15] =
            f2bf(acc[nt][r] + pbv[r]);
  }
  __syncthreads();   // CTP complete; FH/FL dead -> CMB may now use POOL

  // ======================= attention phase (proven R10) ====================
  // softmax(tfw)
  float tf0 = tfw[0], tf1 = tfw[1], tf2 = tfw[2], tf3 = tfw[3];
  float tm = fmaxf(fmaxf(tf0, tf1), fmaxf(tf2, tf3));
  float te0 = __expf(tf0 - tm), te1 = __expf(tf1 - tm);
  float te2 = __expf(tf2 - tm), te3 = __expf(tf3 - tm);
  float tden = te0 + te1 + te2 + te3;

  const unsigned short* arow = &CTP[(w * 16 + l15) * 264];

#pragma unroll 1
  for (int i = 0; i < 4; ++i) {
#define WFRAG(m, nt, s)                                                        \
  (*(const short8*)&wb[((i * 4 + (m)) << 12) + ((nt)*16 + l15) * 64 +          \
                       (s)*32 + lq * 8])

    float wi = ((i == 0) ? te0 : (i == 1) ? te1 : (i == 2) ? te2 : te3) / tden;

    float bqv[4], bkv[4], bvv[4];
#pragma unroll
    for (int nt = 0; nt < 4; ++nt) {
      int d = i * 64 + nt * 16 + l15;
      bqv[nt] = bq[d]; bkv[nt] = bk[d]; bvv[nt] = bv[d];
    }

    // ---- q = ctx[:,i] @ wq^T + bq ----
    float4v qacc[4] = {zf, zf, zf, zf};
    __builtin_amdgcn_s_setprio(1);
#pragma unroll
    for (int s = 0; s < 2; ++s) {
      short8 af = *(const short8*)&arow[i * 64 + s * 32 + lq * 8];
#pragma unroll
      for (int nt = 0; nt < 4; ++nt)
        qacc[nt] = __builtin_amdgcn_mfma_f32_16x16x32_bf16(af, WFRAG(0, nt, s),
                                                           qacc[nt], 0, 0, 0);
    }
    __builtin_amdgcn_s_setprio(0);
#pragma unroll
    for (int nt = 0; nt < 4; ++nt)
#pragma unroll
      for (int r = 0; r < 4; ++r) qacc[nt][r] += bqv[nt];

    // hoist K/V B-fragments into registers
    short8 kf[2][4], vf[2][4];
#pragma unroll
    for (int s = 0; s < 2; ++s)
#pragma unroll
      for (int nt = 0; nt < 4; ++nt) {
        kf[s][nt] = WFRAG(1, nt, s);
        vf[s][nt] = WFRAG(2, nt, s);
      }

    // ---- per key j: k/v GEMMs, scores, un-normalized softmax-weighted V ----
    float4v oacc[4] = {zf, zf, zf, zf};
    float lsum[4][4] = {{0,0,0,0},{0,0,0,0},{0,0,0,0},{0,0,0,0}};

#pragma unroll 1
    for (int j = 0; j < 4; ++j) {
      float4v kacc[4] = {zf, zf, zf, zf};
      float4v vacc[4] = {zf, zf, zf, zf};
      __builtin_amdgcn_s_setprio(1);
#pragma unroll
      for (int s = 0; s < 2; ++s) {
        short8 af = *(const short8*)&arow[j * 64 + s * 32 + lq * 8];
#pragma unroll
        for (int nt = 0; nt < 4; ++nt) {
          kacc[nt] = __builtin_amdgcn_mfma_f32_16x16x32_bf16(af, kf[s][nt],
                                                             kacc[nt], 0, 0, 0);
          vacc[nt] = __builtin_amdgcn_mfma_f32_16x16x32_bf16(af, vf[s][nt],
                                                             vacc[nt], 0, 0, 0);
        }
      }
      __builtin_amdgcn_s_setprio(0);
#pragma unroll
      for (int nt = 0; nt < 4; ++nt)
#pragma unroll
        for (int r = 0; r < 4; ++r) {
          float p = qacc[nt][r] * (kacc[nt][r] + bkv[nt]);
          p = group16_sum(p) * 0.25f;          // 1/sqrt(HD); |p| small -> no max-sub
          float e = __expf(p);
          lsum[nt][r] += e;
          oacc[nt][r] += e * (vacc[nt][r] + bvv[nt]);
        }
    }

    // ---- o (C/D layout) -> plain [m][d] slab (wave-private, fence only) ----
    lds_fence();   // order vs previous iteration's OSP reads
#pragma unroll
    for (int nt = 0; nt < 4; ++nt)
#pragma unroll
      for (int r = 0; r < 4; ++r)
        OSP[w][(lq * 4 + r) * 72 + nt * 16 + l15] = f2bf(oacc[nt][r] / lsum[nt][r]);
    lds_fence();

    // ---- o2 = o @ wo^T ----
    float4v o2[4] = {zf, zf, zf, zf};
    __builtin_amdgcn_s_setprio(1);
#pragma unroll
    for (int s = 0; s < 2; ++s) {
      short8 af = *(const short8*)&OSP[w][l15 * 72 + s * 32 + lq * 8];
#pragma unroll
      for (int nt = 0; nt < 4; ++nt)
        o2[nt] = __builtin_amdgcn_mfma_f32_16x16x32_bf16(af, WFRAG(3, nt, s),
                                                         o2[nt], 0, 0, 0);
    }
    __builtin_amdgcn_s_setprio(0);

    float bov[4], ngv[4], nbv[4];
#pragma unroll
    for (int nt = 0; nt < 4; ++nt) {
      int d = i * 64 + nt * 16 + l15;
      bov[nt] = bo[d]; ngv[nt] = ng[d]; nbv[nt] = nb[d];
    }

    // ---- + bo + residual (plain CTP read) ----
    float rr[4][4];
#pragma unroll
    for (int nt = 0; nt < 4; ++nt)
#pragma unroll
      for (int r = 0; r < 4; ++r) {
        float qin = bf2f(CTP[(w * 16 + lq * 4 + r) * 264 + i * 64 + nt * 16 + l15]);
        rr[nt][r] = o2[nt][r] + bov[nt] + qin;
      }

    // ---- per-module LN; scale by wi; store to CMB (proven indices) ----
#pragma unroll
    for (int r = 0; r < 4; ++r) {
      float sm = group16_sum(rr[0][r] + rr[1][r] + rr[2][r] + rr[3][r]) * (1.0f / 64.0f);
      float vs = 0.0f;
#pragma unroll
      for (int nt = 0; nt < 4; ++nt) { float dx = rr[nt][r] - sm; vs += dx * dx; }
      vs = group16_sum(vs) * (1.0f / 64.0f);
      float inv = rsqrtf(vs + EPSV);
      int rowl = w * 16 + lq * 4 + r;
#pragma unroll
      for (int nt = 0; nt < 4; ++nt) {
        float val = wi * ((rr[nt][r] - sm) * inv * ngv[nt] + nbv[nt]);
        CMB[rowl * 256 + i * 64 + nt * 16 + l15] = f2bf(val);
      }
    }
#undef WFRAG
  }

  // ---- fused final LN over K*D=256 (proven R10 epilogue) ----
  lds_fence();
  float4 g = *(const float4*)&fg[l * 4];
  float4 bb = *(const float4*)&fb[l * 4];
#pragma unroll 1
  for (int rr = 0; rr < 16; ++rr) {
    int rowl = w * 16 + rr;
    ushort4v pk = *(const ushort4v*)&CMB[rowl * 256 + l * 4];
    float vx = bf2f(pk.x), vy = bf2f(pk.y), vz = bf2f(pk.z), vw = bf2f(pk.w);
    float mean = wave_sum64(vx + vy + vz + vw) * (1.0f / 256.0f);
    float dx = vx - mean, dy = vy - mean, dz = vz - mean, dw = vw - mean;
    float var = wave_sum64(dx * dx + dy * dy + dz * dz + dw * dw) * (1.0f / 256.0f);
    float inv = rsqrtf(var + EPSV);
    float4 o;
    o.x = dx * inv * g.x + bb.x;
    o.y = dy * inv * g.y + bb.y;
    o.z = dz * inv * g.z + bb.z;
    o.w = dw * inv * g.w + bb.w;
    *(float4*)&out[((size_t)blockIdx.x * 64 + rowl) * 256 + l * 4] = o;
  }
}

// ---------------------------------------------------------------------------
extern "C" void kernel_launch(void* const* d_in, const int* in_sizes, int n_in,
                              void* d_out, int out_size, void* d_ws, size_t ws_size,
                              hipStream_t stream) {
  const float* feats  = (const float*)d_in[0];
  const float* proj_w = (const float*)d_in[1];
  const float* proj_b = (const float*)d_in[2];
  const float* wq  = (const float*)d_in[3];
  const float* wk  = (const float*)d_in[4];
  const float* wv  = (const float*)d_in[5];
  const float* bq  = (const float*)d_in[6];
  const float* bk  = (const float*)d_in[7];
  const float* bv  = (const float*)d_in[8];
  const float* wo  = (const float*)d_in[9];
  const float* bo  = (const float*)d_in[10];
  const float* ng  = (const float*)d_in[11];
  const float* nb  = (const float*)d_in[12];
  const float* tfw = (const float*)d_in[13];
  const float* fg  = (const float*)d_in[14];
  const float* fb  = (const float*)d_in[15];
  float* out = (float*)d_out;

  // workspace: wph 64KB | wpl 64KB | wb 128KB (ctx buffer no longer needed)
  unsigned short* wph = (unsigned short*)d_ws;
  unsigned short* wpl = wph + 32768;
  unsigned short* wb  = wpl + 32768;

  prep_kernel<<<384, 256, 0, stream>>>(proj_w, wq, wk, wv, wo, wph, wpl, wb);
  fused_kernel<<<1024, 256, 0, stream>>>(feats, wph, wpl, proj_b, wb,
                                         bq, bk, bv, bo, ng, nb, tfw,
                                         fg, fb, out);
}

// Round 12
// 339.563 us; speedup vs baseline: 1.2717x; 1.0117x over previous
//
#include <hip/hip_runtime.h>
#include <math.h>

// Sizes: K=4, B=1024, C=128, T=64, D=64, H=4, HD=16, N=B*D=65536
#define EPSV 1e-5f

typedef __attribute__((ext_vector_type(8))) short short8;   // 8 x bf16 (4 VGPRs)
typedef __attribute__((ext_vector_type(4))) float float4v;  // MFMA 16x16 acc
typedef __attribute__((ext_vector_type(4))) unsigned short ushort4v;

__device__ __forceinline__ unsigned short f2bf(float f) {   // fp32 -> bf16 RNE
  unsigned int x = __float_as_uint(f);
  return (unsigned short)((x + 0x7fffu + ((x >> 16) & 1u)) >> 16);
}
__device__ __forceinline__ float bf2f(unsigned short u) {
  return __uint_as_float(((unsigned int)u) << 16);
}
__device__ __forceinline__ float wave_sum64(float v) {
  v += __shfl_xor(v, 1);
  v += __shfl_xor(v, 2);
  v += __shfl_xor(v, 4);
  v += __shfl_xor(v, 8);
  v += __shfl_xor(v, 16);
  v += __shfl_xor(v, 32);
  return v;
}
// sum over the 16-lane group (lanes sharing l>>4) — session-proven shfl form.
__device__ __forceinline__ float group16_sum(float v) {
  v += __shfl_xor(v, 1);
  v += __shfl_xor(v, 2);
  v += __shfl_xor(v, 4);
  v += __shfl_xor(v, 8);
  return v;
}
// Wave-level LDS fence: orders this wave's LDS ops (lanes lockstep, DS pipe
// in-order per wave; the "memory" clobber stops compiler reordering).
__device__ __forceinline__ void lds_fence() {
  asm volatile("s_waitcnt lgkmcnt(0)" ::: "memory");
}

// ---------------------------------------------------------------------------
// Kernel 0: one-time weight prep (proven).
// ---------------------------------------------------------------------------
__global__ __launch_bounds__(256) void prep_kernel(
    const float* __restrict__ pw, const float* __restrict__ wq,
    const float* __restrict__ wk, const float* __restrict__ wv,
    const float* __restrict__ wo, unsigned short* __restrict__ wph,
    unsigned short* __restrict__ wpl, unsigned short* __restrict__ wb) {
  int idx = blockIdx.x * 256 + threadIdx.x;
  if (idx < 32768) {
    float f = pw[idx];
    unsigned short h = f2bf(f);
    wph[idx] = h;
    wpl[idx] = f2bf(f - bf2f(h));
  } else {
    int e = idx - 32768;
    int mat = e >> 14, i = (e >> 12) & 3, r = e & 4095;
    const float* src = (mat == 0) ? wq : (mat == 1) ? wk : (mat == 2) ? wv : wo;
    wb[((i * 4 + mat) << 12) + r] = f2bf(src[(i << 12) + r]);
  }
}

// ---------------------------------------------------------------------------
// Kernel 1: FUSED proj + attention + final LN — FULLY BARRIER-FREE.
// Wave w owns module k=w end-to-end: proj computes the whole 64x64 tile for
// module w (writing ctx rows w*16..w*16+15 of CTP = exactly the rows wave w
// consumes in the attn phase). All LDS is wave-private; zero __syncthreads.
// Per-wave 8KB pool: proj staging FHW/FLW (64x32 hi/lo chunk, XOR-swizzled,
// <=2-way banks) aliases the attn-phase CMB slab (16x256 bf16).
// LDS: POOL 32768 + CTP 33792 + OSP 9216 = 75776 B -> 2 blocks/CU.
// All operand bytes / accumulation order bit-identical to R11.
// ---------------------------------------------------------------------------
__global__ __launch_bounds__(256, 2) void fused_kernel(
    const float* __restrict__ feats, const unsigned short* __restrict__ wph,
    const unsigned short* __restrict__ wpl, const float* __restrict__ pb,
    const unsigned short* __restrict__ wb,
    const float* __restrict__ bq, const float* __restrict__ bk,
    const float* __restrict__ bv, const float* __restrict__ bo,
    const float* __restrict__ ng, const float* __restrict__ nb,
    const float* __restrict__ tfw, const float* __restrict__ fg,
    const float* __restrict__ fb, float* __restrict__ out) {
  __shared__ __align__(16) unsigned short POOL[4 * 4096];   // 8KB per wave
  __shared__ __align__(16) unsigned short CTP[64 * 264];    // ctx rows (bf16)
  __shared__ __align__(16) unsigned short OSP[4][16 * 72];  // per-wave o slab

  int tid = threadIdx.x;
  int w = tid >> 6, l = tid & 63;
  int l15 = l & 15, lq = l >> 4;
  const float4v zf = {0.0f, 0.0f, 0.0f, 0.0f};

  unsigned short* const WPOOL = POOL + w * 4096;
  unsigned short* const FHW = WPOOL;          // [64 t][32 c] hi, swizzled
  unsigned short* const FLW = WPOOL + 2048;   // lo
  unsigned short* const CMBW = WPOOL;         // attn phase: 16x256 comb rows

  // ================= proj phase: module k = w, whole 64x64 tile ============
  {
    const float* fsrc = feats + ((size_t)w * 1024 + blockIdx.x) * 8192;
    const unsigned short* whp = wph + w * 8192;
    const unsigned short* wlp = wpl + w * 8192;

    float4v acc[4][4];                        // [mt][nt]
#pragma unroll
    for (int mt = 0; mt < 4; ++mt)
#pragma unroll
      for (int nt = 0; nt < 4; ++nt) acc[mt][nt] = zf;

    int sur = lq ^ ((l15 >> 1) & 3);          // read-side swizzled unit

#pragma unroll 1
    for (int kc = 0; kc < 4; ++kc) {
      lds_fence();                            // prior kc's reads done (in-order DS)
#pragma unroll
      for (int u = 0; u < 4; ++u) {
        float fv[8];
#pragma unroll
        for (int q = 0; q < 8; ++q)
          fv[q] = fsrc[(kc * 32 + u * 8 + q) * 64 + l];   // coalesced
        short8 hv, lv;
#pragma unroll
        for (int q = 0; q < 8; ++q) {
          unsigned short h = f2bf(fv[q]);
          hv[q] = (short)h;
          lv[q] = (short)f2bf(fv[q] - bf2f(h));
        }
        int su = u ^ ((l >> 1) & 3);          // write-side swizzle (t = l)
        *(short8*)&FHW[l * 32 + su * 8] = hv;
        *(short8*)&FLW[l * 32 + su * 8] = lv;
      }
      lds_fence();

      __builtin_amdgcn_s_setprio(1);
#pragma unroll
      for (int mt = 0; mt < 4; ++mt) {
        short8 ah = *(const short8*)&whp[(mt * 16 + l15) * 128 + kc * 32 + lq * 8];
        short8 al = *(const short8*)&wlp[(mt * 16 + l15) * 128 + kc * 32 + lq * 8];
#pragma unroll
        for (int nt = 0; nt < 4; ++nt) {
          short8 bh = *(const short8*)&FHW[(nt * 16 + l15) * 32 + sur * 8];
          short8 bl = *(const short8*)&FLW[(nt * 16 + l15) * 32 + sur * 8];
          acc[mt][nt] = __builtin_amdgcn_mfma_f32_16x16x32_bf16(ah, bh, acc[mt][nt], 0, 0, 0);
          acc[mt][nt] = __builtin_amdgcn_mfma_f32_16x16x32_bf16(ah, bl, acc[mt][nt], 0, 0, 0);
          acc[mt][nt] = __builtin_amdgcn_mfma_f32_16x16x32_bf16(al, bh, acc[mt][nt], 0, 0, 0);
        }
      }
      __builtin_amdgcn_s_setprio(0);
    }

    // d = mt*16+lq*4+r, t = nt*16+l15 -> CTP row w*16 + mt*4 + lq (wave-own),
    // col r*64 + t. Bit-identical bf16 values to the R11 path.
#pragma unroll
    for (int mt = 0; mt < 4; ++mt) {
      float4 pbm = *(const float4*)&pb[w * 64 + mt * 16 + lq * 4];
#pragma unroll
      for (int nt = 0; nt < 4; ++nt) {
        float pr[4] = {pbm.x, pbm.y, pbm.z, pbm.w};
#pragma unroll
        for (int r = 0; r < 4; ++r)
          CTP[(w * 16 + mt * 4 + lq) * 264 + r * 64 + nt * 16 + l15] =
              f2bf(acc[mt][nt][r] + pr[r]);
      }
    }
  }
  lds_fence();   // CTP rows (wave-own) visible; FHW/FLW dead -> CMBW may reuse

  // ======================= attention phase (proven R11) ====================
  float tf0 = tfw[0], tf1 = tfw[1], tf2 = tfw[2], tf3 = tfw[3];
  float tm = fmaxf(fmaxf(tf0, tf1), fmaxf(tf2, tf3));
  float te0 = __expf(tf0 - tm), te1 = __expf(tf1 - tm);
  float te2 = __expf(tf2 - tm), te3 = __expf(tf3 - tm);
  float tden = te0 + te1 + te2 + te3;

  const unsigned short* arow = &CTP[(w * 16 + l15) * 264];

#pragma unroll 1
  for (int i = 0; i < 4; ++i) {
#define WFRAG(m, nt, s)                                                        \
  (*(const short8*)&wb[((i * 4 + (m)) << 12) + ((nt)*16 + l15) * 64 +          \
                       (s)*32 + lq * 8])

    float wi = ((i == 0) ? te0 : (i == 1) ? te1 : (i == 2) ? te2 : te3) / tden;

    float bqv[4], bkv[4], bvv[4];
#pragma unroll
    for (int nt = 0; nt < 4; ++nt) {
      int d = i * 64 + nt * 16 + l15;
      bqv[nt] = bq[d]; bkv[nt] = bk[d]; bvv[nt] = bv[d];
    }

    // ---- q = ctx[:,i] @ wq^T + bq ----
    float4v qacc[4] = {zf, zf, zf, zf};
    __builtin_amdgcn_s_setprio(1);
#pragma unroll
    for (int s = 0; s < 2; ++s) {
      short8 af = *(const short8*)&arow[i * 64 + s * 32 + lq * 8];
#pragma unroll
      for (int nt = 0; nt < 4; ++nt)
        qacc[nt] = __builtin_amdgcn_mfma_f32_16x16x32_bf16(af, WFRAG(0, nt, s),
                                                           qacc[nt], 0, 0, 0);
    }
    __builtin_amdgcn_s_setprio(0);
#pragma unroll
    for (int nt = 0; nt < 4; ++nt)
#pragma unroll
      for (int r = 0; r < 4; ++r) qacc[nt][r] += bqv[nt];

    // hoist K/V B-fragments into registers
    short8 kf[2][4], vf[2][4];
#pragma unroll
    for (int s = 0; s < 2; ++s)
#pragma unroll
      for (int nt = 0; nt < 4; ++nt) {
        kf[s][nt] = WFRAG(1, nt, s);
        vf[s][nt] = WFRAG(2, nt, s);
      }

    // ---- per key j: k/v GEMMs, scores, un-normalized softmax-weighted V ----
    float4v oacc[4] = {zf, zf, zf, zf};
    float lsum[4][4] = {{0,0,0,0},{0,0,0,0},{0,0,0,0},{0,0,0,0}};

#pragma unroll 1
    for (int j = 0; j < 4; ++j) {
      float4v kacc[4] = {zf, zf, zf, zf};
      float4v vacc[4] = {zf, zf, zf, zf};
      __builtin_amdgcn_s_setprio(1);
#pragma unroll
      for (int s = 0; s < 2; ++s) {
        short8 af = *(const short8*)&arow[j * 64 + s * 32 + lq * 8];
#pragma unroll
        for (int nt = 0; nt < 4; ++nt) {
          kacc[nt] = __builtin_amdgcn_mfma_f32_16x16x32_bf16(af, kf[s][nt],
                                                             kacc[nt], 0, 0, 0);
          vacc[nt] = __builtin_amdgcn_mfma_f32_16x16x32_bf16(af, vf[s][nt],
                                                             vacc[nt], 0, 0, 0);
        }
      }
      __builtin_amdgcn_s_setprio(0);
#pragma unroll
      for (int nt = 0; nt < 4; ++nt)
#pragma unroll
        for (int r = 0; r < 4; ++r) {
          float p = qacc[nt][r] * (kacc[nt][r] + bkv[nt]);
          p = group16_sum(p) * 0.25f;          // 1/sqrt(HD); |p| small -> no max-sub
          float e = __expf(p);
          lsum[nt][r] += e;
          oacc[nt][r] += e * (vacc[nt][r] + bvv[nt]);
        }
    }

    // ---- o (C/D layout) -> plain [m][d] slab (wave-private, fence only) ----
    lds_fence();   // order vs previous iteration's OSP reads
#pragma unroll
    for (int nt = 0; nt < 4; ++nt)
#pragma unroll
      for (int r = 0; r < 4; ++r)
        OSP[w][(lq * 4 + r) * 72 + nt * 16 + l15] = f2bf(oacc[nt][r] / lsum[nt][r]);
    lds_fence();

    // ---- o2 = o @ wo^T ----
    float4v o2[4] = {zf, zf, zf, zf};
    __builtin_amdgcn_s_setprio(1);
#pragma unroll
    for (int s = 0; s < 2; ++s) {
      short8 af = *(const short8*)&OSP[w][l15 * 72 + s * 32 + lq * 8];
#pragma unroll
      for (int nt = 0; nt < 4; ++nt)
        o2[nt] = __builtin_amdgcn_mfma_f32_16x16x32_bf16(af, WFRAG(3, nt, s),
                                                         o2[nt], 0, 0, 0);
    }
    __builtin_amdgcn_s_setprio(0);

    float bov[4], ngv[4], nbv[4];
#pragma unroll
    for (int nt = 0; nt < 4; ++nt) {
      int d = i * 64 + nt * 16 + l15;
      bov[nt] = bo[d]; ngv[nt] = ng[d]; nbv[nt] = nb[d];
    }

    // ---- + bo + residual (plain CTP read) ----
    float rr[4][4];
#pragma unroll
    for (int nt = 0; nt < 4; ++nt)
#pragma unroll
      for (int r = 0; r < 4; ++r) {
        float qin = bf2f(CTP[(w * 16 + lq * 4 + r) * 264 + i * 64 + nt * 16 + l15]);
        rr[nt][r] = o2[nt][r] + bov[nt] + qin;
      }

    // ---- per-module LN; scale by wi; store to wave-private CMBW ----
#pragma unroll
    for (int r = 0; r < 4; ++r) {
      float sm = group16_sum(rr[0][r] + rr[1][r] + rr[2][r] + rr[3][r]) * (1.0f / 64.0f);
      float vs = 0.0f;
#pragma unroll
      for (int nt = 0; nt < 4; ++nt) { float dx = rr[nt][r] - sm; vs += dx * dx; }
      vs = group16_sum(vs) * (1.0f / 64.0f);
      float inv = rsqrtf(vs + EPSV);
      int lr = lq * 4 + r;                    // local row 0..15
#pragma unroll
      for (int nt = 0; nt < 4; ++nt) {
        float val = wi * ((rr[nt][r] - sm) * inv * ngv[nt] + nbv[nt]);
        CMBW[lr * 256 + i * 64 + nt * 16 + l15] = f2bf(val);
      }
    }
#undef WFRAG
  }

  // ---- fused final LN over K*D=256 (proven epilogue, wave-private CMBW) ----
  lds_fence();
  float4 g = *(const float4*)&fg[l * 4];
  float4 bb = *(const float4*)&fb[l * 4];
#pragma unroll 1
  for (int rr = 0; rr < 16; ++rr) {
    ushort4v pk = *(const ushort4v*)&CMBW[rr * 256 + l * 4];
    float vx = bf2f(pk.x), vy = bf2f(pk.y), vz = bf2f(pk.z), vw = bf2f(pk.w);
    float mean = wave_sum64(vx + vy + vz + vw) * (1.0f / 256.0f);
    float dx = vx - mean, dy = vy - mean, dz = vz - mean, dw = vw - mean;
    float var = wave_sum64(dx * dx + dy * dy + dz * dz + dw * dw) * (1.0f / 256.0f);
    float inv = rsqrtf(var + EPSV);
    float4 o;
    o.x = dx * inv * g.x + bb.x;
    o.y = dy * inv * g.y + bb.y;
    o.z = dz * inv * g.z + bb.z;
    o.w = dw * inv * g.w + bb.w;
    *(float4*)&out[((size_t)blockIdx.x * 64 + w * 16 + rr) * 256 + l * 4] = o;
  }
}

// ---------------------------------------------------------------------------
extern "C" void kernel_launch(void* const* d_in, const int* in_sizes, int n_in,
                              void* d_out, int out_size, void* d_ws, size_t ws_size,
                              hipStream_t stream) {
  const float* feats  = (const float*)d_in[0];
  const float* proj_w = (const float*)d_in[1];
  const float* proj_b = (const float*)d_in[2];
  const float* wq  = (const float*)d_in[3];
  const float* wk  = (const float*)d_in[4];
  const float* wv  = (const float*)d_in[5];
  const float* bq  = (const float*)d_in[6];
  const float* bk  = (const float*)d_in[7];
  const float* bv  = (const float*)d_in[8];
  const float* wo  = (const float*)d_in[9];
  const float* bo  = (const float*)d_in[10];
  const float* ng  = (const float*)d_in[11];
  const float* nb  = (const float*)d_in[12];
  const float* tfw = (const float*)d_in[13];
  const float* fg  = (const float*)d_in[14];
  const float* fb  = (const float*)d_in[15];
  float* out = (float*)d_out;

  // workspace: wph 64KB | wpl 64KB | wb 128KB
  unsigned short* wph = (unsigned short*)d_ws;
  unsigned short* wpl = wph + 32768;
  unsigned short* wb  = wpl + 32768;

  prep_kernel<<<384, 256, 0, stream>>>(proj_w, wq, wk, wv, wo, wph, wpl, wb);
  fused_kernel<<<1024, 256, 0, stream>>>(feats, wph, wpl, proj_b, wb,
                                         bq, bk, bv, bo, ng, nb, tfw,
                                         fg, fb, out);
}